// Round 10
// baseline (1711.080 us; speedup 1.0000x reference)
//
#include <hip/hip_runtime.h>
#include <cstdint>
#include <cstddef>

typedef unsigned short u16;
typedef unsigned char u8;
typedef unsigned int u32;

typedef short s16x8 __attribute__((ext_vector_type(8)));
typedef float f32x4 __attribute__((ext_vector_type(4)));

#define MF(a,b,c) __builtin_amdgcn_mfma_f32_16x16x32_bf16((a),(b),(c),0,0,0)

// ---------------- helpers ----------------
__device__ __forceinline__ float b2f(u16 h){ u32 u = ((u32)h)<<16; float f; __builtin_memcpy(&f,&u,4); return f; }
__device__ __forceinline__ u16 f2b(float x){ u32 u; __builtin_memcpy(&u,&x,4); u += 0x7fffu + ((u>>16)&1u); return (u16)(u>>16); }
__device__ __forceinline__ float sigf(float x){ return __builtin_amdgcn_rcpf(1.f+__expf(-x)); }
__device__ __forceinline__ float tanh2(float x){
  float ax=fabsf(x); float e=__expf(-2.f*ax);
  float r=(1.f-e)*__builtin_amdgcn_rcpf(1.f+e);
  return x<0.f? -r : r;
}

// coherent write-through stores (no L2 dirtying; visible at coherence point)
__device__ __forceinline__ void st_u16_coh(u16* p, u16 v){
  asm volatile("global_store_short %0, %1, off sc0 sc1" :: "v"(p), "v"((u32)v) : "memory");
}
__device__ __forceinline__ void st_f32_coh(float* p, float v){
  asm volatile("global_store_dword %0, %1, off sc0 sc1" :: "v"(p), "v"(v) : "memory");
}
// pinned 16B load (weights -> registers, non-rematerializable)
__device__ __forceinline__ s16x8 gload16(const u16* p){
  s16x8 r;
  asm volatile("global_load_dwordx4 %0, %1, off" : "=v"(r) : "v"(p) : "memory");
  return r;
}
// coherent 16B load: reads at coherence point (never stale)
__device__ __forceinline__ s16x8 gload16_coh(const u16* p){
  s16x8 r;
  asm volatile("global_load_dwordx4 %0, %1, off sc0 sc1" : "=v"(r) : "v"(p) : "memory");
  return r;
}
// non-temporal 16B load: streamed data, minimal L2 footprint (don't evict Wi)
__device__ __forceinline__ s16x8 gload16_nt(const u16* p){
  s16x8 r;
  asm volatile("global_load_dwordx4 %0, %1, off nt" : "=v"(r) : "v"(p) : "memory");
  return r;
}

// ---------------- mask dtype detection + packed mask codes ----------------
__global__ void detect_mask_mode(const u8* raw, int n, int* flag){
  __shared__ int cnt;
  int tid = threadIdx.x;
  if(tid==0) cnt=0;
  __syncthreads();
  int c=0;
  for(int i=tid;i<n;i+=blockDim.x) c += (raw[i]!=0);
  atomicAdd(&cnt, c);
  __syncthreads();
  if(tid==0) *flag = (cnt > (n>>2)) ? 1 : 0;  // 1 => byte-per-element layout
}

// code[i] = done | main<<1 | mainNext<<2
__global__ void build_mcode(const void* done_raw, const void* main_raw, u8* code, int n, const int* flag){
  int mode = *flag;
  for(int i = blockIdx.x*blockDim.x + threadIdx.x; i<n; i += gridDim.x*blockDim.x){
    u8 d, m, m2;
    if(mode){
      d = ((const u8*)done_raw)[i]!=0; m = ((const u8*)main_raw)[i]!=0;
      m2 = (i+256<n) ? (((const u8*)main_raw)[i+256]!=0) : (u8)0;
    } else {
      d = ((const int*)done_raw)[i]!=0; m = ((const int*)main_raw)[i]!=0;
      m2 = (i+256<n) ? (((const int*)main_raw)[i+256]!=0) : (u8)0;
    }
    code[i] = d | (m<<1) | (m2<<2);
  }
}

__global__ void zero_flags(int* p, int n){
  int i = threadIdx.x;
  if(i<n) p[i]=0;
}

// ---------------- conversions ----------------
__global__ void cvt_f32_bf16(const float* __restrict__ in, u16* __restrict__ out, int n4){
  int i = blockIdx.x*blockDim.x + threadIdx.x;
  if(i < n4){
    float4 v = ((const float4*)in)[i];
    ushort4 o;
    o.x=f2b(v.x); o.y=f2b(v.y); o.z=f2b(v.z); o.w=f2b(v.w);
    ((ushort4*)out)[i]=o;
  }
}

// in [R][C] f32  ->  out [C][R] bf16
__global__ void transpose_to_bf16(const float* __restrict__ in, u16* __restrict__ out, int R, int C){
  __shared__ float tile[64][65];
  int c0 = blockIdx.x*64, r0 = blockIdx.y*64;
  int tx = threadIdx.x & 63, ty = threadIdx.x >> 6;   // 256 threads
  for(int i=ty;i<64;i+=4) tile[i][tx] = in[(size_t)(r0+i)*C + c0 + tx];
  __syncthreads();
  for(int i=ty;i<64;i+=4) out[(size_t)(c0+i)*R + r0 + tx] = f2b(tile[tx][i]);
}

__global__ void init_hsel(const float* __restrict__ h1in, const float* __restrict__ h2in,
                          const u8* __restrict__ mcode, u16* __restrict__ hsel0){
  int i = blockIdx.x*blockDim.x + threadIdx.x;
  if(i < 256*1024){
    int row = i >> 10;
    hsel0[i] = f2b((mcode[row]&2) ? h1in[i] : h2in[i]);
  }
}

// ---------------- fused persistent kernel: x-GEMM + recurrence ----------------
// Structure = R9 exactly, with the L2-residency fixes:
//  * out stores are sc0sc1 write-through AND issued after the flag release
//    (no L2 dirtying, off the chain's critical path);
//  * x staging loads are nt (non-temporal) so the once-streamed x never
//    evicts the t-invariant Wi slice (1MB/XCD) from L2;
//  * Wi loads stay plain cached -> L2-hit every step.
__global__ __launch_bounds__(512) __attribute__((amdgpu_waves_per_eu(2,2)))
void lstm_fused(
    const u16* __restrict__ xb, const u16* __restrict__ WiT,
    const u16* __restrict__ Wht, const float* __restrict__ bias,
    u16* __restrict__ hs0, u16* __restrict__ hs1,
    const float* __restrict__ c1i, const float* __restrict__ h1i,
    const float* __restrict__ c2i, const float* __restrict__ h2i,
    const u8* __restrict__ mcode, float* __restrict__ out,
    int* __restrict__ ready)
{
  __shared__ u16 As[32768];        // 64 KB, time-multiplexed (h / zpart / x)
  float* zpart = (float*)As;

  const int bid = blockIdx.x;
  const int rg = bid >> 5, jg = bid & 31;
  const int r0 = rg << 5, j0 = jg << 5;
  const int tid = threadIdx.x, wid = tid >> 6, lane = tid & 63;
  const int l15 = lane & 15, hi = lane >> 4;
  const int gate = wid >> 1, kg = wid & 1;
  const int srow = tid >> 4, sc16 = tid & 15;   // staging persona
  const int erow = tid >> 5, ecol = tid & 31;   // epilogue persona

  // ---- Wh^T fragments (once): 32 x s16x8 = 128 VGPRs, asm-pinned ----
  s16x8 breg[2][16];
  {
    #pragma unroll
    for(int n=0;n<2;n++){
      const u16* wp = Wht + ((size_t)(gate*1024 + j0 + n*16 + l15))*1024 + kg*512 + hi*8;
      #pragma unroll
      for(int kk=0;kk<16;kk++) breg[n][kk] = gload16(wp + kk*32);
    }
    asm volatile("s_waitcnt vmcnt(0)" ::: "memory");
    __builtin_amdgcn_sched_barrier(0);
  }

  // ---- Wi^T streaming pointers (t-invariant -> L2-hit every step) ----
  const u16* wip0 = WiT + ((size_t)(gate*1024 + j0      + l15))*1024 + kg*512 + hi*8;
  const u16* wip1 = WiT + ((size_t)(gate*1024 + j0 + 16 + l15))*1024 + kg*512 + hi*8;
  const float bias0 = kg ? 0.f : bias[gate*1024 + j0      + l15];
  const float bias1 = kg ? 0.f : bias[gate*1024 + j0 + 16 + l15];

  // ---- states into registers (once) ----
  float c1r[2],c2r[2],h1r[2],h2r[2];
  #pragma unroll
  for(int e=0;e<2;e++){
    size_t sidx = (size_t)(r0 + e*16 + erow)*1024 + j0 + ecol;
    c1r[e]=c1i[sidx]; c2r[e]=c2i[sidx]; h1r[e]=h1i[sidx]; h2r[e]=h2i[sidx];
  }

  // ---- LDS pointers (t-invariant; x and h share layout/swizzle) ----
  u16* pSh = &As[sc16*256 + ((srow ^ (sc16&7))<<3)];
  const u16* pAe = &As[kg*16384 + hi*256 + ((l15 ^  hi   )<<3)];
  const u16* pAo = &As[kg*16384 + hi*256 + ((l15 ^ (4+hi))<<3)];
  float* pzw = &zpart[((gate*2+kg)*32 + hi*4)*33 + l15];
  const float* pzr = &zpart[erow*33 + ecol];

  int* flag = ready + rg*32;

  f32x4 acc00, acc01, acc10, acc11;   // carry x@Wi+b into the next critical zone

  // ---- x phase (free zone): stage x rows into As (nt), acc = x@Wi + b ----
  auto xphase = [&](const u16* xrow){
    s16x8 x0 = gload16_nt(xrow + (0*16+sc16)*8);
    s16x8 x1 = gload16_nt(xrow + (1*16+sc16)*8);
    s16x8 x2 = gload16_nt(xrow + (2*16+sc16)*8);
    s16x8 x3 = gload16_nt(xrow + (3*16+sc16)*8);
    s16x8 x4 = gload16_nt(xrow + (4*16+sc16)*8);
    s16x8 x5 = gload16_nt(xrow + (5*16+sc16)*8);
    s16x8 x6 = gload16_nt(xrow + (6*16+sc16)*8);
    s16x8 x7 = gload16_nt(xrow + (7*16+sc16)*8);
    asm volatile("s_waitcnt vmcnt(0)" ::: "memory");   // asm loads: manual wait
    *(s16x8*)(pSh + 0*4096) = x0;  *(s16x8*)(pSh + 1*4096) = x1;
    *(s16x8*)(pSh + 2*4096) = x2;  *(s16x8*)(pSh + 3*4096) = x3;
    *(s16x8*)(pSh + 4*4096) = x4;  *(s16x8*)(pSh + 5*4096) = x5;
    *(s16x8*)(pSh + 6*4096) = x6;  *(s16x8*)(pSh + 7*4096) = x7;
    __syncthreads();
    acc00 = (f32x4){bias0,bias0,bias0,bias0};
    acc01 = (f32x4){bias1,bias1,bias1,bias1};
    acc10 = acc00; acc11 = acc01;
    // 4 groups x 4 kk; plain Wi loads (L2-resident; compiler-scheduled waits)
    #pragma unroll
    for(int g=0;g<4;g++){
      s16x8 w0[4], w1[4];
      #pragma unroll
      for(int j=0;j<4;j++){
        w0[j] = *(const s16x8*)(wip0 + (g*4+j)*32);
        w1[j] = *(const s16x8*)(wip1 + (g*4+j)*32);
      }
      #pragma unroll
      for(int j=0;j<4;j++){
        int kk = g*4+j;
        const u16* p = (kk&1) ? pAo : pAe;
        s16x8 a0 = *(const s16x8*)(p + kk*1024);
        s16x8 a1 = *(const s16x8*)(p + kk*1024 + 128);
        acc00 = MF(a0, w0[j], acc00);
        acc01 = MF(a0, w1[j], acc01);
        acc10 = MF(a1, w0[j], acc10);
        acc11 = MF(a1, w1[j], acc11);
      }
    }
  };

  // ---- prologue: x-part for step 0 ----
  xphase(xb + (size_t)(r0+srow)*1024);

  for(int t=0;t<128;t++){
    u8 cd0 = mcode[t*256 + r0 + erow];
    u8 cd1 = mcode[t*256 + r0 + 16 + erow];

    // ---- chain wait (single spinner; others park at the barrier) ----
    if(t>0 && tid==0){
      while(__hip_atomic_load(flag, __ATOMIC_RELAXED, __HIP_MEMORY_SCOPE_AGENT) < 32*t)
        __builtin_amdgcn_s_sleep(1);
    }
    __syncthreads();                       // also: all x-MFMA As reads retired
    __builtin_amdgcn_sched_barrier(0);

    const u16* hinp = (t&1) ? hs1 : hs0;
    u16* houtp = (t&1) ? hs0 : hs1;

    // ---- stage h(t-1): coherent point-reads -> swizzled LDS (R6 exact) ----
    {
      const u16* hrow = hinp + (size_t)(r0+srow)*1024;
      s16x8 h0 = gload16_coh(hrow + (0*16+sc16)*8);
      s16x8 h1 = gload16_coh(hrow + (1*16+sc16)*8);
      s16x8 h2 = gload16_coh(hrow + (2*16+sc16)*8);
      s16x8 h3 = gload16_coh(hrow + (3*16+sc16)*8);
      s16x8 h4 = gload16_coh(hrow + (4*16+sc16)*8);
      s16x8 h5 = gload16_coh(hrow + (5*16+sc16)*8);
      s16x8 h6 = gload16_coh(hrow + (6*16+sc16)*8);
      s16x8 h7 = gload16_coh(hrow + (7*16+sc16)*8);
      asm volatile("s_waitcnt vmcnt(0)" ::: "memory");
      *(s16x8*)(pSh + 0*4096) = h0;  *(s16x8*)(pSh + 1*4096) = h1;
      *(s16x8*)(pSh + 2*4096) = h2;  *(s16x8*)(pSh + 3*4096) = h3;
      *(s16x8*)(pSh + 4*4096) = h4;  *(s16x8*)(pSh + 5*4096) = h5;
      *(s16x8*)(pSh + 6*4096) = h6;  *(s16x8*)(pSh + 7*4096) = h7;
    }
    __syncthreads();

    // ---- h-MFMA: extend acc with h@Wh (this wave's K-half) ----
    #pragma unroll
    for(int kk=0;kk<16;kk++){
      const u16* p = (kk&1) ? pAo : pAe;
      s16x8 a0 = *(const s16x8*)(p + kk*1024);
      s16x8 a1 = *(const s16x8*)(p + kk*1024 + 128);
      acc00 = MF(a0, breg[0][kk], acc00);
      acc01 = MF(a0, breg[1][kk], acc01);
      acc10 = MF(a1, breg[0][kk], acc10);
      acc11 = MF(a1, breg[1][kk], acc11);
    }
    __syncthreads();   // all h-MFMA As reads retired -> zpart alias safe

    // ---- K-half partial exchange: zpart[gate*2+kg][row][33] (aliases As) ----
    #pragma unroll
    for(int j=0;j<4;j++){
      pzw[      j*33     ] = acc00[j];
      pzw[      j*33 + 16] = acc01[j];
      pzw[528 + j*33     ] = acc10[j];
      pzw[528 + j*33 + 16] = acc11[j];
    }
    __syncthreads();

    // ---- epilogue: z sums (bias pre-folded), gates, state update ----
    float nhv[2];
    #pragma unroll
    for(int e=0;e<2;e++){
      u8 cd = e ? cd1 : cd0;
      float zi  = pzr[   0 + e*528] + pzr[1056 + e*528];
      float zf_ = pzr[2112 + e*528] + pzr[3168 + e*528];
      float zg  = pzr[4224 + e*528] + pzr[5280 + e*528];
      float zo  = pzr[6336 + e*528] + pzr[7392 + e*528];
      bool d_ = cd & 1, m_ = cd & 2, m2 = cd & 4;
      float co = m_ ? c1r[e] : c2r[e];
      float nc = sigf(zf_)*co + sigf(zi)*tanh2(zg);
      float nhx = sigf(zo)*tanh2(nc);
      nhv[e] = nhx;
      float n1c = m_?nc:c1r[e], n2c = m_?c2r[e]:nc;
      float n1h = m_?nhx:h1r[e], n2h = m_?h2r[e]:nhx;
      if(d_){ n1c=0.f; n2c=0.f; n1h=0.f; n2h=0.f; }
      c1r[e]=n1c; c2r[e]=n2c; h1r[e]=n1h; h2r[e]=n2h;
      if(t<127){
        int grow = r0 + e*16 + erow;
        st_u16_coh(&houtp[(size_t)grow*1024 + j0 + ecol], f2b(m2 ? n1h : n2h));
      }
    }
    asm volatile("s_waitcnt vmcnt(0)" ::: "memory");   // h at coherence point
    __syncthreads();                                   // epilogue zpart reads done
    if(t<127 && tid==0)
      __hip_atomic_fetch_add(flag, 1, __ATOMIC_RELAXED, __HIP_MEMORY_SCOPE_AGENT);

    // ---- off critical path: out stores (sc0sc1, no L2 dirty) + next x-part ----
    #pragma unroll
    for(int e=0;e<2;e++){
      int grow = r0 + e*16 + erow;
      st_f32_coh(&out[(size_t)(t*256 + grow)*1024 + j0 + ecol], nhv[e]);
    }
    if(t<127)
      xphase(xb + (size_t)((t+1)*256 + r0 + srow)*1024);
  }
}

// ---------------- host ----------------
extern "C" void kernel_launch(void* const* d_in, const int* in_sizes, int n_in,
                              void* d_out, int out_size, void* d_ws, size_t ws_size,
                              hipStream_t stream){
  const float* x   = (const float*)d_in[0];
  const float* c1i = (const float*)d_in[1];
  const float* h1i = (const float*)d_in[2];
  const float* c2i = (const float*)d_in[3];
  const float* h2i = (const float*)d_in[4];
  const float* Wi  = (const float*)d_in[5];
  const float* Wh  = (const float*)d_in[6];
  const float* bias= (const float*)d_in[7];
  const void* done_raw = d_in[8];
  const void* main_raw = d_in[9];
  float* out = (float*)d_out;

  char* ws = (char*)d_ws;
  size_t off=0;
  auto alloc=[&](size_t sz)->char*{ char* p = ws+off; off += (sz+255)&~(size_t)255; return p; };

  u16* xb   = (u16*)alloc(33554432ull*2);        // x as bf16 [32768][1024]
  u16* WiT  = (u16*)alloc(4096ull*1024*2);       // Wi^T bf16 [4096][1024]
  u16* WhT  = (u16*)alloc(4096ull*1024*2);       // Wh^T bf16 [4096][1024]
  u16* hs0  = (u16*)alloc(262144ull*2);
  u16* hs1  = (u16*)alloc(262144ull*2);
  u8* mcode = (u8*)alloc(32768);
  int* flag = (int*)alloc(256);
  int* ready= (int*)alloc(1024);
  (void)ws_size;

  detect_mask_mode<<<1,256,0,stream>>>((const u8*)done_raw, 32768, flag);
  build_mcode<<<64,256,0,stream>>>(done_raw, main_raw, mcode, 32768, flag);
  cvt_f32_bf16<<<32768,256,0,stream>>>(x, xb, 8388608);
  transpose_to_bf16<<<dim3(64,16),256,0,stream>>>(Wi, WiT, 1024, 4096);
  transpose_to_bf16<<<dim3(64,16),256,0,stream>>>(Wh, WhT, 1024, 4096);
  init_hsel<<<1024,256,0,stream>>>(h1i, h2i, mcode, hs0);
  zero_flags<<<1,256,0,stream>>>(ready, 256);

  lstm_fused<<<256,512,0,stream>>>(xb, WiT, WhT, bias, hs0, hs1,
                                   c1i, h1i, c2i, h2i, mcode, out, ready);
}

// Round 11
// 1234.068 us; speedup vs baseline: 1.3865x; 1.3865x over previous
//
#include <hip/hip_runtime.h>
#include <cstdint>
#include <cstddef>

typedef unsigned short u16;
typedef unsigned char u8;
typedef unsigned int u32;

typedef short s16x8 __attribute__((ext_vector_type(8)));
typedef float f32x4 __attribute__((ext_vector_type(4)));

#define MF(a,b,c) __builtin_amdgcn_mfma_f32_16x16x32_bf16((a),(b),(c),0,0,0)

// ---------------- helpers ----------------
__device__ __forceinline__ float b2f(u16 h){ u32 u = ((u32)h)<<16; float f; __builtin_memcpy(&f,&u,4); return f; }
__device__ __forceinline__ u16 f2b(float x){ u32 u; __builtin_memcpy(&u,&x,4); u += 0x7fffu + ((u>>16)&1u); return (u16)(u>>16); }
// IEEE f16 <-> f32 (Zx storage: |z| small, f16 err ~2e-3 << threshold)
__device__ __forceinline__ u16 f2h(float x){ _Float16 h = (_Float16)x; u16 u; __builtin_memcpy(&u,&h,2); return u; }
__device__ __forceinline__ float h2f(u16 v){ _Float16 h; __builtin_memcpy(&h,&v,2); return (float)h; }
__device__ __forceinline__ float sigf(float x){ return __builtin_amdgcn_rcpf(1.f+__expf(-x)); }
__device__ __forceinline__ float tanh2(float x){
  float ax=fabsf(x); float e=__expf(-2.f*ax);
  float r=(1.f-e)*__builtin_amdgcn_rcpf(1.f+e);
  return x<0.f? -r : r;
}

typedef __attribute__((address_space(1))) const void gvoid_t;
typedef __attribute__((address_space(3))) void lvoid_t;
__device__ __forceinline__ void gl_lds16(const u16* src, u16* dst){
  __builtin_amdgcn_global_load_lds((gvoid_t*)src, (lvoid_t*)dst, 16, 0, 0);
}

// coherent write-through store (no L2 dirtying; visible at coherence point)
__device__ __forceinline__ void st_u16_coh(u16* p, u16 v){
  asm volatile("global_store_short %0, %1, off sc0 sc1" :: "v"(p), "v"((u32)v) : "memory");
}
__device__ __forceinline__ void st_f32_coh(float* p, float v){
  asm volatile("global_store_dword %0, %1, off sc0 sc1" :: "v"(p), "v"(v) : "memory");
}
// pinned (non-rematerializable) 16B load
__device__ __forceinline__ s16x8 gload16(const u16* p){
  s16x8 r;
  asm volatile("global_load_dwordx4 %0, %1, off" : "=v"(r) : "v"(p) : "memory");
  return r;
}
// coherent 16B load: reads at coherence point (never stale)
__device__ __forceinline__ s16x8 gload16_coh(const u16* p){
  s16x8 r;
  asm volatile("global_load_dwordx4 %0, %1, off sc0 sc1" : "=v"(r) : "v"(p) : "memory");
  return r;
}

// ---------------- mask dtype detection + canonicalization ----------------
__global__ void detect_mask_mode(const u8* raw, int n, int* flag){
  __shared__ int cnt;
  int tid = threadIdx.x;
  if(tid==0) cnt=0;
  __syncthreads();
  int c=0;
  for(int i=tid;i<n;i+=blockDim.x) c += (raw[i]!=0);
  atomicAdd(&cnt, c);
  __syncthreads();
  if(tid==0) *flag = (cnt > (n>>2)) ? 1 : 0;  // 1 => byte-per-element layout
}

__global__ void convert_masks(const void* done_raw, const void* main_raw, u8* done_u8, u8* main_u8, int n, const int* flag){
  int mode = *flag;
  for(int i = blockIdx.x*blockDim.x + threadIdx.x; i<n; i += gridDim.x*blockDim.x){
    u8 d, m;
    if(mode){ d = ((const u8*)done_raw)[i]!=0; m = ((const u8*)main_raw)[i]!=0; }
    else    { d = ((const int*)done_raw)[i]!=0; m = ((const int*)main_raw)[i]!=0; }
    done_u8[i]=d; main_u8[i]=m;
  }
}

__global__ void zero_flags(int* p, int n){
  int i = threadIdx.x;
  if(i<n) p[i]=0;
}

// ---------------- conversions ----------------
__global__ void cvt_f32_bf16(const float* __restrict__ in, u16* __restrict__ out, int n4){
  int i = blockIdx.x*blockDim.x + threadIdx.x;
  if(i < n4){
    float4 v = ((const float4*)in)[i];
    ushort4 o;
    o.x=f2b(v.x); o.y=f2b(v.y); o.z=f2b(v.z); o.w=f2b(v.w);
    ((ushort4*)out)[i]=o;
  }
}

// in [R][C] f32  ->  out [C][R] bf16
__global__ void transpose_to_bf16(const float* __restrict__ in, u16* __restrict__ out, int R, int C){
  __shared__ float tile[64][65];
  int c0 = blockIdx.x*64, r0 = blockIdx.y*64;
  int tx = threadIdx.x & 63, ty = threadIdx.x >> 6;   // 256 threads
  for(int i=ty;i<64;i+=4) tile[i][tx] = in[(size_t)(r0+i)*C + c0 + tx];
  __syncthreads();
  for(int i=ty;i<64;i+=4) out[(size_t)(c0+i)*R + r0 + tx] = f2b(tile[tx][i]);
}

__global__ void init_hsel(const float* __restrict__ h1in, const float* __restrict__ h2in,
                          const u8* __restrict__ mmain, u16* __restrict__ hsel0){
  int i = blockIdx.x*blockDim.x + threadIdx.x;
  if(i < 256*1024){
    int row = i >> 10;
    hsel0[i] = f2b(mmain[row] ? h1in[i] : h2in[i]);
  }
}

// ---------------- phase 1: Zx = x @ Wi + b  (K-major LDS, BK=64, f16 out) ----------------
// LDS layout: chunk c = s*128 + r (s = 16B K-slot 0..7, r = row 0..127), 16B per chunk.
// MFMA reads are lane-contiguous 16B (2-way bank alias = free); staging dest linear.
__global__ __launch_bounds__(256) void gemm_zx(const u16* __restrict__ A, const u16* __restrict__ Bt,
                                               const float* __restrict__ bias, u16* __restrict__ C){
  __shared__ u16 As[8192];   // 16 KB
  __shared__ u16 Bs[8192];   // 16 KB
  const int nbx = 32;                 // N/128
  const int nwg = 8192;               // (M/128)*(N/128)
  int gid = blockIdx.x;
  int per = nwg>>3;
  int g2 = (gid&7)*per + (gid>>3);    // XCD-contiguous remap (bijective)
  int tpg = 8*nbx;
  int grp = g2/tpg, w = g2%tpg;
  int brow = grp*8 + (w & 7);
  int bcol = w >> 3;
  int row0 = brow<<7, col0 = bcol<<7;

  int tid=threadIdx.x, wid=tid>>6, lane=tid&63;
  int l15=lane&15, hi=lane>>4;
  int wm=(wid>>1)<<6, wn=(wid&1)<<6;

  f32x4 acc[4][4];
  #pragma unroll
  for(int m=0;m<4;m++)
    #pragma unroll
    for(int n=0;n<4;n++) acc[m][n]=(f32x4){0.f,0.f,0.f,0.f};

  for(int k0=0;k0<1024;k0+=64){
    __syncthreads();
    #pragma unroll
    for(int i=0;i<4;i++){
      int cb = (wid*4+i)*64;
      int c  = cb + lane;
      int r  = c & 127, s = c >> 7;
      gl_lds16(A + (size_t)(row0+r)*1024 + k0 + s*8, &As[cb*8]);
    }
    #pragma unroll
    for(int i=0;i<4;i++){
      int cb = (wid*4+i)*64;
      int c  = cb + lane;
      int r  = c & 127, s = c >> 7;
      gl_lds16(Bt + (size_t)(col0+r)*1024 + k0 + s*8, &Bs[cb*8]);
    }
    __syncthreads();
    #pragma unroll
    for(int kk=0;kk<2;kk++){
      s16x8 a[4], b[4];
      #pragma unroll
      for(int m=0;m<4;m++) a[m] = *(const s16x8*)&As[(kk*4+hi)*1024 + (wm+m*16+l15)*8];
      #pragma unroll
      for(int n=0;n<4;n++) b[n] = *(const s16x8*)&Bs[(kk*4+hi)*1024 + (wn+n*16+l15)*8];
      #pragma unroll
      for(int m=0;m<4;m++)
        #pragma unroll
        for(int n=0;n<4;n++)
          acc[m][n] = MF(a[m],b[n],acc[m][n]);
    }
  }
  #pragma unroll
  for(int m=0;m<4;m++){
    #pragma unroll
    for(int n=0;n<4;n++){
      int c = col0+wn+n*16+l15;
      float bv = bias[c];
      #pragma unroll
      for(int j=0;j<4;j++){
        int r = row0+wm+m*16+hi*4+j;
        C[(size_t)r*4096+c] = f2h(acc[m][n][j] + bv);
      }
    }
  }
}

// ---------------- phase 2: persistent recurrent kernel (R6-exact, Zx f16) ----------------
// 256 blocks x 512 threads (8 waves), 1 block/CU. rg=bid&7 (32 rows), jg=bid>>3
// (32 hcols). Wave: gate=wid>>1, kg=wid&1 (K-half). breg 128 VGPR/wave via pinned
// asm loads; waves_per_eu(2,2) = 256-reg budget. Sync (proven R5/R6): producer
// sc0sc1 write-through h + vmcnt(0) + barrier + relaxed flag; consumer spins
// relaxed then sc0sc1 point-reads -> swizzled LDS. No cache maintenance anywhere.
__global__ __launch_bounds__(512) __attribute__((amdgpu_waves_per_eu(2,2)))
void lstm_persist(
    const u16* __restrict__ Zx, const u16* __restrict__ Wht,
    u16* __restrict__ hs0, u16* __restrict__ hs1,
    const float* __restrict__ c1i, const float* __restrict__ h1i,
    const float* __restrict__ c2i, const float* __restrict__ h2i,
    const u8* __restrict__ mdone, const u8* __restrict__ mmain,
    float* __restrict__ out, int* __restrict__ ready)
{
  __shared__ u16 As[32768];            // 64 KB: 128 chunks x [32 rows x 16B], XOR-swizzled
  __shared__ float zpart[4*2*32*33];   // 33 KB: [gate][kg][row][33] partial sums

  const int bid = blockIdx.x;
  const int rg = bid & 7, jg = bid >> 3;
  const int r0 = rg << 5, j0 = jg << 5;
  const int tid = threadIdx.x, wid = tid >> 6, lane = tid & 63;
  const int l15 = lane & 15, hi = lane >> 4;
  const int gate = wid >> 1, kg = wid & 1;
  const int srow = tid >> 4, sc16 = tid & 15;   // staging: row 0..31, col16 0..15
  const int erow = tid >> 5, ecol = tid & 31;   // epilogue: rows, 32 cols

  // ---- Wh^T fragments: this wave's (gate, K-half) x 32 cols: 128 VGPRs ----
  s16x8 breg[2][16];
  {
    #pragma unroll
    for(int n=0;n<2;n++){
      const u16* wp = Wht + ((size_t)(gate*1024 + j0 + n*16 + l15))*1024 + kg*512 + hi*8;
      #pragma unroll
      for(int kk=0;kk<16;kk++) breg[n][kk] = gload16(wp + kk*32);
    }
    asm volatile("s_waitcnt vmcnt(0)" ::: "memory");
    __builtin_amdgcn_sched_barrier(0);
  }

  // ---- states into registers (thread-stationary across all 128 steps) ----
  float c1r[2],c2r[2],h1r[2],h2r[2];
  #pragma unroll
  for(int e=0;e<2;e++){
    size_t sidx = (size_t)(r0 + e*16 + erow)*1024 + j0 + ecol;
    c1r[e]=c1i[sidx]; c2r[e]=c2i[sidx]; h1r[e]=h1i[sidx]; h2r[e]=h2i[sidx];
  }

  int* flag = ready + rg*32;    // 128B-spaced per-rg counters

  for(int t=0;t<128;t++){
    // ---- prefetch step-local immutable inputs (f16 Zx is L3-resident) ----
    float zr[4][2]; u8 md[2], mm[2], mm2[2];
    #pragma unroll
    for(int e=0;e<2;e++){
      int gb = t*256 + r0 + e*16 + erow;
      size_t base = (size_t)gb*4096 + j0 + ecol;
      #pragma unroll
      for(int g=0; g<4; g++)
        zr[g][e] = h2f(Zx[base + g*1024]);
      md[e]=mdone[gb]; mm[e]=mmain[gb];
      mm2[e] = (t<127) ? mmain[gb+256] : (u8)0;
    }

    // ---- chain wait (single spinner; others park at the barrier) ----
    if(t>0 && tid==0){
      while(__hip_atomic_load(flag, __ATOMIC_RELAXED, __HIP_MEMORY_SCOPE_AGENT) < 32*t)
        __builtin_amdgcn_s_sleep(1);
    }
    __syncthreads();
    __builtin_amdgcn_sched_barrier(0);

    const u16* hin = (t&1) ? hs1 : hs0;
    u16* hout = (t&1) ? hs0 : hs1;

    // ---- stage h tile: 8 coherent 16B loads/thread -> swizzled LDS,
    //      ds_writes interleaved with counted vmcnt ----
    {
      const u16* hrow = hin + (size_t)(r0+srow)*1024;
      s16x8 v[8];
      #pragma unroll
      for(int kc=0;kc<8;kc++) v[kc] = gload16_coh(hrow + (kc*16+sc16)*8);
      asm volatile("s_waitcnt vmcnt(4)" ::: "memory");
      #pragma unroll
      for(int kc=0;kc<4;kc++){
        int chunk = kc*16+sc16;
        *(s16x8*)&As[chunk*256 + ((srow ^ (chunk&7))<<3)] = v[kc];
      }
      asm volatile("s_waitcnt vmcnt(0)" ::: "memory");
      #pragma unroll
      for(int kc=4;kc<8;kc++){
        int chunk = kc*16+sc16;
        *(s16x8*)&As[chunk*256 + ((srow ^ (chunk&7))<<3)] = v[kc];
      }
    }
    __syncthreads();   // tile staged

    // ---- recurrent GEMM: this wave's K-half, 64 MFMA, B from registers ----
    f32x4 acc[2][2];
    #pragma unroll
    for(int m=0;m<2;m++)
      #pragma unroll
      for(int n=0;n<2;n++) acc[m][n]=(f32x4){0.f,0.f,0.f,0.f};
    #pragma unroll
    for(int kk=0;kk<16;kk++){
      int c0 = (kg*16 + kk)*4 + hi;                 // 16B chunk 0..127
      s16x8 a0 = *(const s16x8*)&As[c0*256 + ((l15      ^ (c0&7))<<3)];
      s16x8 a1 = *(const s16x8*)&As[c0*256 + (((16+l15) ^ (c0&7))<<3)];
      acc[0][0] = MF(a0, breg[0][kk], acc[0][0]);
      acc[0][1] = MF(a0, breg[1][kk], acc[0][1]);
      acc[1][0] = MF(a1, breg[0][kk], acc[1][0]);
      acc[1][1] = MF(a1, breg[1][kk], acc[1][1]);
    }
    // no barrier needed: zpart is a separate LDS region

    // ---- K-half partial exchange: zpart[gate][kg][row][33] ----
    #pragma unroll
    for(int m=0;m<2;m++)
      #pragma unroll
      for(int n=0;n<2;n++)
        #pragma unroll
        for(int j=0;j<4;j++){
          int row = m*16 + hi*4 + j;
          zpart[((gate*2+kg)*32 + row)*33 + n*16 + l15] = acc[m][n][j];
        }
    __syncthreads();

    // ---- epilogue: sum K-halves, gates, state update; h stores first ----
    float nhv[2];
    #pragma unroll
    for(int e=0;e<2;e++){
      int row = e*16 + erow;
      float zi  = zr[0][e] + zpart[((0)*32+row)*33 + ecol] + zpart[((1)*32+row)*33 + ecol];
      float zf_ = zr[1][e] + zpart[((2)*32+row)*33 + ecol] + zpart[((3)*32+row)*33 + ecol];
      float zg  = zr[2][e] + zpart[((4)*32+row)*33 + ecol] + zpart[((5)*32+row)*33 + ecol];
      float zo  = zr[3][e] + zpart[((6)*32+row)*33 + ecol] + zpart[((7)*32+row)*33 + ecol];
      bool m_ = mm[e]!=0, d_ = md[e]!=0;
      float co = m_ ? c1r[e] : c2r[e];
      float nc = sigf(zf_)*co + sigf(zi)*tanh2(zg);
      float nhx = sigf(zo)*tanh2(nc);
      nhv[e] = nhx;
      float n1c = m_?nc:c1r[e], n2c = m_?c2r[e]:nc;
      float n1h = m_?nhx:h1r[e], n2h = m_?h2r[e]:nhx;
      if(d_){ n1c=0.f; n2c=0.f; n1h=0.f; n2h=0.f; }
      c1r[e]=n1c; c2r[e]=n2c; h1r[e]=n1h; h2r[e]=n2h;
      if(t<127)
        st_u16_coh(&hout[(size_t)(r0+row)*1024 + j0 + ecol], f2b(mm2[e] ? n1h : n2h));
    }
    asm volatile("s_waitcnt vmcnt(0)" ::: "memory");   // h at coherence point
    __syncthreads();
    if(t<127 && tid==0)
      __hip_atomic_fetch_add(flag, 1, __ATOMIC_RELAXED, __HIP_MEMORY_SCOPE_AGENT);

    // ---- out store off the critical path (drains during next spin) ----
    #pragma unroll
    for(int e=0;e<2;e++){
      int gb = t*256 + r0 + e*16 + erow;
      st_f32_coh(&out[(size_t)gb*1024 + j0 + ecol], nhv[e]);
    }
  }
}

// ---------------- host ----------------
extern "C" void kernel_launch(void* const* d_in, const int* in_sizes, int n_in,
                              void* d_out, int out_size, void* d_ws, size_t ws_size,
                              hipStream_t stream){
  const float* x   = (const float*)d_in[0];
  const float* c1i = (const float*)d_in[1];
  const float* h1i = (const float*)d_in[2];
  const float* c2i = (const float*)d_in[3];
  const float* h2i = (const float*)d_in[4];
  const float* Wi  = (const float*)d_in[5];
  const float* Wh  = (const float*)d_in[6];
  const float* bias= (const float*)d_in[7];
  const void* done_raw = d_in[8];
  const void* main_raw = d_in[9];
  float* out = (float*)d_out;

  char* ws = (char*)d_ws;
  size_t off=0;
  auto alloc=[&](size_t sz)->char*{ char* p = ws+off; off += (sz+255)&~(size_t)255; return p; };

  u16* xb   = (u16*)alloc(33554432ull*2);        // x as bf16 [32768][1024]
  u16* WiT  = (u16*)alloc(4096ull*1024*2);       // Wi^T bf16 [4096][1024]
  u16* WhT  = (u16*)alloc(4096ull*1024*2);       // Wh^T bf16 [4096][1024]
  u16* hs0  = (u16*)alloc(262144ull*2);
  u16* hs1  = (u16*)alloc(262144ull*2);
  u8* dmask = (u8*)alloc(32768);
  u8* mmask = (u8*)alloc(32768);
  int* flag = (int*)alloc(256);
  int* ready= (int*)alloc(1024);
  u16* Zx   = (u16*)alloc(268435456ull);         // Zx f16 [32768][4096] -- L3-resident

  detect_mask_mode<<<1,256,0,stream>>>((const u8*)done_raw, 32768, flag);
  convert_masks<<<64,256,0,stream>>>(done_raw, main_raw, dmask, mmask, 32768, flag);
  cvt_f32_bf16<<<32768,256,0,stream>>>(x, xb, 8388608);
  transpose_to_bf16<<<dim3(64,16),256,0,stream>>>(Wi, WiT, 1024, 4096);
  transpose_to_bf16<<<dim3(64,16),256,0,stream>>>(Wh, WhT, 1024, 4096);
  init_hsel<<<1024,256,0,stream>>>(h1i, h2i, mmask, hs0);
  zero_flags<<<1,256,0,stream>>>(ready, 256);

  gemm_zx<<<8192,256,0,stream>>>(xb, WiT, bias, Zx);

  lstm_persist<<<256,512,0,stream>>>(Zx,WhT,hs0,hs1,c1i,h1i,c2i,h2i,dmask,mmask,out,ready);
}

// Round 12
// 1034.589 us; speedup vs baseline: 1.6539x; 1.1928x over previous
//
#include <hip/hip_runtime.h>
#include <cstdint>
#include <cstddef>

typedef unsigned short u16;
typedef unsigned char u8;
typedef unsigned int u32;

typedef short s16x8 __attribute__((ext_vector_type(8)));
typedef float f32x4 __attribute__((ext_vector_type(4)));

#define MF(a,b,c) __builtin_amdgcn_mfma_f32_16x16x32_bf16((a),(b),(c),0,0,0)

// ---------------- helpers ----------------
__device__ __forceinline__ float b2f(u16 h){ u32 u = ((u32)h)<<16; float f; __builtin_memcpy(&f,&u,4); return f; }
__device__ __forceinline__ u16 f2b(float x){ u32 u; __builtin_memcpy(&u,&x,4); u += 0x7fffu + ((u>>16)&1u); return (u16)(u>>16); }
// IEEE f16 <-> f32 (Zx storage: |z| small, f16 err ~2e-3 << threshold)
__device__ __forceinline__ u16 f2h(float x){ _Float16 h = (_Float16)x; u16 u; __builtin_memcpy(&u,&h,2); return u; }
__device__ __forceinline__ float h2f(u16 v){ _Float16 h; __builtin_memcpy(&h,&v,2); return (float)h; }
__device__ __forceinline__ float sigf(float x){ return __builtin_amdgcn_rcpf(1.f+__expf(-x)); }
__device__ __forceinline__ float tanh2(float x){
  float ax=fabsf(x); float e=__expf(-2.f*ax);
  float r=(1.f-e)*__builtin_amdgcn_rcpf(1.f+e);
  return x<0.f? -r : r;
}

typedef __attribute__((address_space(1))) const void gvoid_t;
typedef __attribute__((address_space(3))) void lvoid_t;
__device__ __forceinline__ void gl_lds16(const u16* src, u16* dst){
  __builtin_amdgcn_global_load_lds((gvoid_t*)src, (lvoid_t*)dst, 16, 0, 0);
}

// coherent write-through store (no L2 dirtying; visible at coherence point)
__device__ __forceinline__ void st_u16_coh(u16* p, u16 v){
  asm volatile("global_store_short %0, %1, off sc0 sc1" :: "v"(p), "v"((u32)v) : "memory");
}
__device__ __forceinline__ void st_f32_coh(float* p, float v){
  asm volatile("global_store_dword %0, %1, off sc0 sc1" :: "v"(p), "v"(v) : "memory");
}
// pinned (non-rematerializable) 16B load
__device__ __forceinline__ s16x8 gload16(const u16* p){
  s16x8 r;
  asm volatile("global_load_dwordx4 %0, %1, off" : "=v"(r) : "v"(p) : "memory");
  return r;
}
// coherent 16B load: reads at coherence point (never stale)
__device__ __forceinline__ s16x8 gload16_coh(const u16* p){
  s16x8 r;
  asm volatile("global_load_dwordx4 %0, %1, off sc0 sc1" : "=v"(r) : "v"(p) : "memory");
  return r;
}

// ---------------- mask dtype detection + canonicalization ----------------
__global__ void detect_mask_mode(const u8* raw, int n, int* flag){
  __shared__ int cnt;
  int tid = threadIdx.x;
  if(tid==0) cnt=0;
  __syncthreads();
  int c=0;
  for(int i=tid;i<n;i+=blockDim.x) c += (raw[i]!=0);
  atomicAdd(&cnt, c);
  __syncthreads();
  if(tid==0) *flag = (cnt > (n>>2)) ? 1 : 0;  // 1 => byte-per-element layout
}

__global__ void convert_masks(const void* done_raw, const void* main_raw, u8* done_u8, u8* main_u8, int n, const int* flag){
  int mode = *flag;
  for(int i = blockIdx.x*blockDim.x + threadIdx.x; i<n; i += gridDim.x*blockDim.x){
    u8 d, m;
    if(mode){ d = ((const u8*)done_raw)[i]!=0; m = ((const u8*)main_raw)[i]!=0; }
    else    { d = ((const int*)done_raw)[i]!=0; m = ((const int*)main_raw)[i]!=0; }
    done_u8[i]=d; main_u8[i]=m;
  }
}

__global__ void zero_flags(int* p, int n){
  int i = threadIdx.x;
  if(i<n) p[i]=0;
}

// ---------------- conversions ----------------
__global__ void cvt_f32_bf16(const float* __restrict__ in, u16* __restrict__ out, int n4){
  int i = blockIdx.x*blockDim.x + threadIdx.x;
  if(i < n4){
    float4 v = ((const float4*)in)[i];
    ushort4 o;
    o.x=f2b(v.x); o.y=f2b(v.y); o.z=f2b(v.z); o.w=f2b(v.w);
    ((ushort4*)out)[i]=o;
  }
}

// in [R][C] f32  ->  out [C][R] bf16
__global__ void transpose_to_bf16(const float* __restrict__ in, u16* __restrict__ out, int R, int C){
  __shared__ float tile[64][65];
  int c0 = blockIdx.x*64, r0 = blockIdx.y*64;
  int tx = threadIdx.x & 63, ty = threadIdx.x >> 6;   // 256 threads
  for(int i=ty;i<64;i+=4) tile[i][tx] = in[(size_t)(r0+i)*C + c0 + tx];
  __syncthreads();
  for(int i=ty;i<64;i+=4) out[(size_t)(c0+i)*R + r0 + tx] = f2b(tile[tx][i]);
}

__global__ void init_hsel(const float* __restrict__ h1in, const float* __restrict__ h2in,
                          const u8* __restrict__ mmain, u16* __restrict__ hsel0){
  int i = blockIdx.x*blockDim.x + threadIdx.x;
  if(i < 256*1024){
    int row = i >> 10;
    hsel0[i] = f2b(mmain[row] ? h1in[i] : h2in[i]);
  }
}

// ---------------- phase 1: Zx = x @ Wi + b  (R6-exact m97-style, f16 out) ----------------
__global__ __launch_bounds__(256) void gemm_zx(const u16* __restrict__ A, const u16* __restrict__ Bt,
                                               const float* __restrict__ bias, u16* __restrict__ C){
  __shared__ u16 As[128*32];
  __shared__ u16 Bs[128*32];
  const int nbx = 32;                // N/128
  const int nwg = 8192;              // (M/128)*(N/128), divisible by 8
  int gid = blockIdx.x;
  int per = nwg>>3;
  int g2 = (gid&7)*per + (gid>>3);   // XCD-contiguous remap (bijective: nwg%8==0)
  int tpg = 8*nbx;                   // 8-row supergroup x all cols
  int grp = g2/tpg, w = g2%tpg;
  int brow = grp*8 + (w & 7);
  int bcol = w >> 3;
  int row0 = brow<<7, col0 = bcol<<7;

  int tid=threadIdx.x, wid=tid>>6, lane=tid&63;
  int l15=lane&15, hi=lane>>4;
  int wm=(wid>>1)<<6, wn=(wid&1)<<6;

  f32x4 acc[4][4];
  #pragma unroll
  for(int m=0;m<4;m++)
    #pragma unroll
    for(int n=0;n<4;n++) acc[m][n]=(f32x4){0.f,0.f,0.f,0.f};

  for(int k0=0;k0<1024;k0+=32){
    __syncthreads();
    #pragma unroll
    for(int q=0;q<2;q++){
      int cb=q*256+wid*64;
      int ch=cb+lane;
      gl_lds16(A + (size_t)(row0+(ch>>2))*1024 + k0 + (ch&3)*8, &As[cb*8]);
    }
    #pragma unroll
    for(int q=0;q<2;q++){
      int cb=q*256+wid*64;
      int ch=cb+lane;
      gl_lds16(Bt + (size_t)(col0+(ch>>2))*1024 + k0 + (ch&3)*8, &Bs[cb*8]);
    }
    __syncthreads();
    s16x8 a[4], b[4];
    #pragma unroll
    for(int m=0;m<4;m++) a[m] = *(const s16x8*)&As[(wm+m*16+l15)*32 + hi*8];
    #pragma unroll
    for(int n=0;n<4;n++) b[n] = *(const s16x8*)&Bs[(wn+n*16+l15)*32 + hi*8];
    #pragma unroll
    for(int m=0;m<4;m++)
      #pragma unroll
      for(int n=0;n<4;n++)
        acc[m][n] = MF(a[m],b[n],acc[m][n]);
  }
  #pragma unroll
  for(int m=0;m<4;m++){
    #pragma unroll
    for(int n=0;n<4;n++){
      int c = col0+wn+n*16+l15;
      float bv = bias[c];
      #pragma unroll
      for(int j=0;j<4;j++){
        int r = row0+wm+m*16+hi*4+j;
        C[(size_t)r*4096+c] = f2h(acc[m][n][j] + bv);
      }
    }
  }
}

// ---------------- phase 2: persistent recurrent kernel (R11-exact) ----------------
__global__ __launch_bounds__(512) __attribute__((amdgpu_waves_per_eu(2,2)))
void lstm_persist(
    const u16* __restrict__ Zx, const u16* __restrict__ Wht,
    u16* __restrict__ hs0, u16* __restrict__ hs1,
    const float* __restrict__ c1i, const float* __restrict__ h1i,
    const float* __restrict__ c2i, const float* __restrict__ h2i,
    const u8* __restrict__ mdone, const u8* __restrict__ mmain,
    float* __restrict__ out, int* __restrict__ ready)
{
  __shared__ u16 As[32768];            // 64 KB: 128 chunks x [32 rows x 16B], XOR-swizzled
  __shared__ float zpart[4*2*32*33];   // 33 KB: [gate][kg][row][33] partial sums

  const int bid = blockIdx.x;
  const int rg = bid & 7, jg = bid >> 3;
  const int r0 = rg << 5, j0 = jg << 5;
  const int tid = threadIdx.x, wid = tid >> 6, lane = tid & 63;
  const int l15 = lane & 15, hi = lane >> 4;
  const int gate = wid >> 1, kg = wid & 1;
  const int srow = tid >> 4, sc16 = tid & 15;   // staging: row 0..31, col16 0..15
  const int erow = tid >> 5, ecol = tid & 31;   // epilogue: rows, 32 cols

  // ---- Wh^T fragments: this wave's (gate, K-half) x 32 cols: 128 VGPRs ----
  s16x8 breg[2][16];
  {
    #pragma unroll
    for(int n=0;n<2;n++){
      const u16* wp = Wht + ((size_t)(gate*1024 + j0 + n*16 + l15))*1024 + kg*512 + hi*8;
      #pragma unroll
      for(int kk=0;kk<16;kk++) breg[n][kk] = gload16(wp + kk*32);
    }
    asm volatile("s_waitcnt vmcnt(0)" ::: "memory");
    __builtin_amdgcn_sched_barrier(0);
  }

  // ---- states into registers (thread-stationary across all 128 steps) ----
  float c1r[2],c2r[2],h1r[2],h2r[2];
  #pragma unroll
  for(int e=0;e<2;e++){
    size_t sidx = (size_t)(r0 + e*16 + erow)*1024 + j0 + ecol;
    c1r[e]=c1i[sidx]; c2r[e]=c2i[sidx]; h1r[e]=h1i[sidx]; h2r[e]=h2i[sidx];
  }

  int* flag = ready + rg*32;    // 128B-spaced per-rg counters

  for(int t=0;t<128;t++){
    // ---- prefetch step-local immutable inputs (f16 Zx is L3-resident) ----
    float zr[4][2]; u8 md[2], mm[2], mm2[2];
    #pragma unroll
    for(int e=0;e<2;e++){
      int gb = t*256 + r0 + e*16 + erow;
      size_t base = (size_t)gb*4096 + j0 + ecol;
      #pragma unroll
      for(int g=0; g<4; g++)
        zr[g][e] = h2f(Zx[base + g*1024]);
      md[e]=mdone[gb]; mm[e]=mmain[gb];
      mm2[e] = (t<127) ? mmain[gb+256] : (u8)0;
    }

    // ---- chain wait (single spinner; others park at the barrier) ----
    if(t>0 && tid==0){
      while(__hip_atomic_load(flag, __ATOMIC_RELAXED, __HIP_MEMORY_SCOPE_AGENT) < 32*t)
        __builtin_amdgcn_s_sleep(1);
    }
    __syncthreads();
    __builtin_amdgcn_sched_barrier(0);

    const u16* hin = (t&1) ? hs1 : hs0;
    u16* hout = (t&1) ? hs0 : hs1;

    // ---- stage h tile: 8 coherent 16B loads/thread -> swizzled LDS,
    //      ds_writes interleaved with counted vmcnt ----
    {
      const u16* hrow = hin + (size_t)(r0+srow)*1024;
      s16x8 v[8];
      #pragma unroll
      for(int kc=0;kc<8;kc++) v[kc] = gload16_coh(hrow + (kc*16+sc16)*8);
      asm volatile("s_waitcnt vmcnt(4)" ::: "memory");
      #pragma unroll
      for(int kc=0;kc<4;kc++){
        int chunk = kc*16+sc16;
        *(s16x8*)&As[chunk*256 + ((srow ^ (chunk&7))<<3)] = v[kc];
      }
      asm volatile("s_waitcnt vmcnt(0)" ::: "memory");
      #pragma unroll
      for(int kc=4;kc<8;kc++){
        int chunk = kc*16+sc16;
        *(s16x8*)&As[chunk*256 + ((srow ^ (chunk&7))<<3)] = v[kc];
      }
    }
    __syncthreads();   // tile staged

    // ---- recurrent GEMM: this wave's K-half, 64 MFMA, B from registers ----
    f32x4 acc[2][2];
    #pragma unroll
    for(int m=0;m<2;m++)
      #pragma unroll
      for(int n=0;n<2;n++) acc[m][n]=(f32x4){0.f,0.f,0.f,0.f};
    #pragma unroll
    for(int kk=0;kk<16;kk++){
      int c0 = (kg*16 + kk)*4 + hi;                 // 16B chunk 0..127
      s16x8 a0 = *(const s16x8*)&As[c0*256 + ((l15      ^ (c0&7))<<3)];
      s16x8 a1 = *(const s16x8*)&As[c0*256 + (((16+l15) ^ (c0&7))<<3)];
      acc[0][0] = MF(a0, breg[0][kk], acc[0][0]);
      acc[0][1] = MF(a0, breg[1][kk], acc[0][1]);
      acc[1][0] = MF(a1, breg[0][kk], acc[1][0]);
      acc[1][1] = MF(a1, breg[1][kk], acc[1][1]);
    }
    // no barrier needed: zpart is a separate LDS region

    // ---- K-half partial exchange: zpart[gate][kg][row][33] ----
    #pragma unroll
    for(int m=0;m<2;m++)
      #pragma unroll
      for(int n=0;n<2;n++)
        #pragma unroll
        for(int j=0;j<4;j++){
          int row = m*16 + hi*4 + j;
          zpart[((gate*2+kg)*32 + row)*33 + n*16 + l15] = acc[m][n][j];
        }
    __syncthreads();

    // ---- epilogue: sum K-halves, gates, state update; h stores first ----
    float nhv[2];
    #pragma unroll
    for(int e=0;e<2;e++){
      int row = e*16 + erow;
      float zi  = zr[0][e] + zpart[((0)*32+row)*33 + ecol] + zpart[((1)*32+row)*33 + ecol];
      float zf_ = zr[1][e] + zpart[((2)*32+row)*33 + ecol] + zpart[((3)*32+row)*33 + ecol];
      float zg  = zr[2][e] + zpart[((4)*32+row)*33 + ecol] + zpart[((5)*32+row)*33 + ecol];
      float zo  = zr[3][e] + zpart[((6)*32+row)*33 + ecol] + zpart[((7)*32+row)*33 + ecol];
      bool m_ = mm[e]!=0, d_ = md[e]!=0;
      float co = m_ ? c1r[e] : c2r[e];
      float nc = sigf(zf_)*co + sigf(zi)*tanh2(zg);
      float nhx = sigf(zo)*tanh2(nc);
      nhv[e] = nhx;
      float n1c = m_?nc:c1r[e], n2c = m_?c2r[e]:nc;
      float n1h = m_?nhx:h1r[e], n2h = m_?h2r[e]:nhx;
      if(d_){ n1c=0.f; n2c=0.f; n1h=0.f; n2h=0.f; }
      c1r[e]=n1c; c2r[e]=n2c; h1r[e]=n1h; h2r[e]=n2h;
      if(t<127)
        st_u16_coh(&hout[(size_t)(r0+row)*1024 + j0 + ecol], f2b(mm2[e] ? n1h : n2h));
    }
    asm volatile("s_waitcnt vmcnt(0)" ::: "memory");   // h at coherence point
    __syncthreads();
    if(t<127 && tid==0)
      __hip_atomic_fetch_add(flag, 1, __ATOMIC_RELAXED, __HIP_MEMORY_SCOPE_AGENT);

    // ---- out store off the critical path (drains during next spin) ----
    #pragma unroll
    for(int e=0;e<2;e++){
      int gb = t*256 + r0 + e*16 + erow;
      st_f32_coh(&out[(size_t)gb*1024 + j0 + ecol], nhv[e]);
    }
  }
}

// ---------------- host ----------------
extern "C" void kernel_launch(void* const* d_in, const int* in_sizes, int n_in,
                              void* d_out, int out_size, void* d_ws, size_t ws_size,
                              hipStream_t stream){
  const float* x   = (const float*)d_in[0];
  const float* c1i = (const float*)d_in[1];
  const float* h1i = (const float*)d_in[2];
  const float* c2i = (const float*)d_in[3];
  const float* h2i = (const float*)d_in[4];
  const float* Wi  = (const float*)d_in[5];
  const float* Wh  = (const float*)d_in[6];
  const float* bias= (const float*)d_in[7];
  const void* done_raw = d_in[8];
  const void* main_raw = d_in[9];
  float* out = (float*)d_out;

  char* ws = (char*)d_ws;
  size_t off=0;
  auto alloc=[&](size_t sz)->char*{ char* p = ws+off; off += (sz+255)&~(size_t)255; return p; };

  u16* xb   = (u16*)alloc(33554432ull*2);        // x as bf16 [32768][1024]
  u16* WiT  = (u16*)alloc(4096ull*1024*2);       // Wi^T bf16 [4096][1024]
  u16* WhT  = (u16*)alloc(4096ull*1024*2);       // Wh^T bf16 [4096][1024]
  u16* hs0  = (u16*)alloc(262144ull*2);
  u16* hs1  = (u16*)alloc(262144ull*2);
  u8* dmask = (u8*)alloc(32768);
  u8* mmask = (u8*)alloc(32768);
  int* flag = (int*)alloc(256);
  int* ready= (int*)alloc(1024);
  u16* Zx   = (u16*)alloc(268435456ull);         // Zx f16 [32768][4096] -- L3-resident

  detect_mask_mode<<<1,256,0,stream>>>((const u8*)done_raw, 32768, flag);
  convert_masks<<<64,256,0,stream>>>(done_raw, main_raw, dmask, mmask, 32768, flag);
  cvt_f32_bf16<<<32768,256,0,stream>>>(x, xb, 8388608);
  transpose_to_bf16<<<dim3(64,16),256,0,stream>>>(Wi, WiT, 1024, 4096);
  transpose_to_bf16<<<dim3(64,16),256,0,stream>>>(Wh, WhT, 1024, 4096);
  init_hsel<<<1024,256,0,stream>>>(h1i, h2i, mmask, hs0);
  zero_flags<<<1,256,0,stream>>>(ready, 256);

  gemm_zx<<<8192,256,0,stream>>>(xb, WiT, bias, Zx);

  lstm_persist<<<256,512,0,stream>>>(Zx,WhT,hs0,hs1,c1i,h1i,c2i,h2i,dmask,mmask,out,ready);
}